// Round 9
// baseline (89.237 us; speedup 1.0000x reference)
//
#include <hip/hip_runtime.h>
#include <math.h>

#define NCLS 91
#define FDIM 256
#define BINSZ (NCLS * FDIM)        // 23296 floats = 93 KB LDS bins

// ---- workspace layout (4-byte units) ----
#define WS_HIST   BINSZ            // 96 (padded)
#define WS_CURSOR (BINSZ + 96)
#define WS_HPART  (BINSZ + 192)    // 128 * 96
#define WS_PACKED (BINSZ + 192 + 128 * 96)   // uint2 per row

#define HBLK 128
#define SCHUNK 1024

__device__ __forceinline__ float wave_sum64(float ss) {
    #pragma unroll
    for (int m = 1; m < 64; m <<= 1) ss += __shfl_xor(ss, m, 64);
    return ss;
}

// ---- pure-DPP 16-lane butterfly (VALU only, no DS): masks {1,3,7,15} ----
// xor1 = quad_perm[1,0,3,2]=0xB1, xor3 = quad_perm[3,2,1,0]=0x1B,
// xor7 = row_half_mirror=0x141, xor15 = row_mirror=0x140.
template <int CTRL>
__device__ __forceinline__ float dpp_addstep(float v) {
    return v + __int_as_float(__builtin_amdgcn_mov_dpp(
        __float_as_int(v), CTRL, 0xf, 0xf, true));
}
__device__ __forceinline__ float group16_sum(float v) {
    v = dpp_addstep<0xB1>(v);
    v = dpp_addstep<0x1B>(v);
    v = dpp_addstep<0x141>(v);
    v = dpp_addstep<0x140>(v);
    return v;
}

// ---------------- K1: per-block label histogram + zero g_sums ----------------
#define HT 256
extern "C" __global__ void __launch_bounds__(HT)
hist_k(const int* __restrict__ labels, unsigned int* __restrict__ hpart,
       float* __restrict__ g_sums, int nrows)
{
    __shared__ unsigned int lh[NCLS];
    const int tid = threadIdx.x;
    const int z0 = blockIdx.x * 182;
    if (tid < 182 && z0 + tid < BINSZ) g_sums[z0 + tid] = 0.0f;
    for (int i = tid; i < NCLS; i += HT) lh[i] = 0u;
    __syncthreads();
    for (int i = blockIdx.x * HT + tid; i < nrows; i += gridDim.x * HT)
        atomicAdd(&lh[labels[i]], 1u);
    __syncthreads();
    for (int i = tid; i < NCLS; i += HT)
        hpart[blockIdx.x * 96 + i] = lh[i];
}

// ---------------- K2: reduce parts -> hist, exclusive prefix -> cursor ----------------
extern "C" __global__ void __launch_bounds__(128)
prefix_k(const unsigned int* __restrict__ hpart, unsigned int* __restrict__ hist,
         unsigned int* __restrict__ cursor, int nparts)
{
    __shared__ unsigned int h[NCLS];
    const int t = threadIdx.x;
    if (t < NCLS) {
        unsigned int s = 0;
        for (int p = 0; p < nparts; ++p) s += hpart[p * 96 + t];
        h[t] = s;
        hist[t] = s;
    }
    __syncthreads();
    if (t == 0) {
        unsigned int s = 0;
        for (int c = 0; c < NCLS; ++c) { unsigned int v = h[c]; h[c] = s; s += v; }
    }
    __syncthreads();
    if (t < NCLS) cursor[t] = h[t];
}

// ---------------- K3: counting-sort scatter -> packed (row,label) ----------------
extern "C" __global__ void __launch_bounds__(HT)
scatter_k(const int* __restrict__ labels, unsigned int* __restrict__ cursor,
          uint2* __restrict__ packed, int nrows)
{
    __shared__ int ll[SCHUNK];
    __shared__ unsigned int lh[NCLS];
    __shared__ unsigned int base[NCLS];
    const int tid = threadIdx.x;
    const int c0 = blockIdx.x * SCHUNK;
    const int cn = min(SCHUNK, nrows - c0);
    if (cn <= 0) return;

    for (int i = tid; i < NCLS; i += HT) lh[i] = 0u;
    __syncthreads();
    for (int i = tid; i < cn; i += HT) {
        const int l = labels[c0 + i];
        ll[i] = l;
        atomicAdd(&lh[l], 1u);
    }
    __syncthreads();
    for (int i = tid; i < NCLS; i += HT) {
        const unsigned int n = lh[i];
        base[i] = n ? atomicAdd(&cursor[i], n) : 0u;
        lh[i] = 0u;
    }
    __syncthreads();
    for (int i = tid; i < cn; i += HT) {
        const int l = ll[i];
        const unsigned int rank = atomicAdd(&lh[l], 1u);
        packed[base[l] + rank] = make_uint2((unsigned int)(c0 + i), (unsigned int)l);
    }
}

// ---------------- K4 helpers (plain functions, no macros) ----------------
__device__ __forceinline__ void load4(const float* __restrict__ feats, int r,
                                      int l16, float4 (&X)[4]) {
    const float4* rp = (const float4*)(feats + (size_t)r * FDIM);
    #pragma unroll
    for (int k = 0; k < 4; ++k) X[k] = rp[l16 + 16 * k];
}
__device__ __forceinline__ void proc4(const float4 (&X)[4], float4 (&ac)[4]) {
    float ss = 0.f;
    #pragma unroll
    for (int k = 0; k < 4; ++k) {
        ss = fmaf(X[k].x, X[k].x, ss);
        ss = fmaf(X[k].y, X[k].y, ss);
        ss = fmaf(X[k].z, X[k].z, ss);
        ss = fmaf(X[k].w, X[k].w, ss);
    }
    ss = group16_sum(ss);                       // 4 DPP adds, pure VALU
    const float inv = 1.0f / fmaxf(sqrtf(ss), 1e-12f);
    #pragma unroll
    for (int k = 0; k < 4; ++k) {
        ac[k].x = fmaf(X[k].x, inv, ac[k].x);
        ac[k].y = fmaf(X[k].y, inv, ac[k].y);
        ac[k].z = fmaf(X[k].z, inv, ac[k].z);
        ac[k].w = fmaf(X[k].w, inv, ac[k].w);
    }
}

// ---------------- K4: main pass ----------------
// 256 blocks x 1024 thr, 512 sorted rows/block, 32 rows/wave.
// FAST PATH (uniform label in the wave's 32 rows, ~97% of waves):
//   16 lanes per row, 4 rows per step. Lane owns 16 floats of its row;
//   16-lane reduce = 4 DPP adds (pure VALU, ZERO DS — R6's 75us was the
//   6x ds_swizzle ~720cy dependent chain per row). Normalized values
//   accumulate in 16 registers across the run; one LDS-atomic flush/chunk.
#define MPT 1024
#define RPW 32
#define RPB 512

extern "C" __global__ void __launch_bounds__(MPT)
mainpass(const float* __restrict__ feats, const uint2* __restrict__ packed,
         float* __restrict__ g_sums, int nrows)
{
    __shared__ float bins[BINSZ];
    __shared__ int s_cmin, s_cmax;
    const int tid = threadIdx.x;
    const int blk0 = blockIdx.x * RPB;
    if (blk0 >= nrows) return;
    const int blk1 = min(nrows, blk0 + RPB);

    for (int i = tid; i < BINSZ; i += MPT) bins[i] = 0.0f;
    if (tid == 0) { s_cmin = (int)packed[blk0].y; s_cmax = (int)packed[blk1 - 1].y; }
    __syncthreads();

    const int lane = tid & 63;
    const int w = tid >> 6;
    const int i0w = min(blk1, blk0 + w * RPW);
    const int i1w = min(blk1, i0w + RPW);
    const int m = i1w - i0w;

    if (m > 0) {
        int pr = 0, pl = -1;
        if (lane < m) {
            const uint2 e = packed[i0w + lane];
            pr = (int)e.x; pl = (int)e.y;
        }
        const int lfirst = __builtin_amdgcn_readfirstlane(__shfl(pl, 0, 64));
        const int llast  = __builtin_amdgcn_readfirstlane(__shfl(pl, m - 1, 64));

        if (m == RPW && lfirst == llast) {
            // ---------- fast path ----------
            const int g = lane >> 4;          // row-group 0..3
            const int l16 = lane & 15;
            // broadcast the 8 steps' row indices upfront (independent bpermutes)
            const int rr0 = __shfl(pr, 0 * 4 + g, 64);
            const int rr1 = __shfl(pr, 1 * 4 + g, 64);
            const int rr2 = __shfl(pr, 2 * 4 + g, 64);
            const int rr3 = __shfl(pr, 3 * 4 + g, 64);
            const int rr4 = __shfl(pr, 4 * 4 + g, 64);
            const int rr5 = __shfl(pr, 5 * 4 + g, 64);
            const int rr6 = __shfl(pr, 6 * 4 + g, 64);
            const int rr7 = __shfl(pr, 7 * 4 + g, 64);

            float4 A[4], B[4];
            float4 ac[4];
            #pragma unroll
            for (int k = 0; k < 4; ++k) ac[k] = make_float4(0.f, 0.f, 0.f, 0.f);

            load4(feats, rr0, l16, A);
            load4(feats, rr1, l16, B);
            proc4(A, ac); load4(feats, rr2, l16, A);
            proc4(B, ac); load4(feats, rr3, l16, B);
            proc4(A, ac); load4(feats, rr4, l16, A);
            proc4(B, ac); load4(feats, rr5, l16, B);
            proc4(A, ac); load4(feats, rr6, l16, A);
            proc4(B, ac); load4(feats, rr7, l16, B);
            proc4(A, ac);
            proc4(B, ac);

            // one flush per chunk: lane's 16 floats at c*256 + 64k + l16*4 + j
            float* b = bins + lfirst * FDIM + l16 * 4;
            #pragma unroll
            for (int k = 0; k < 4; ++k) {
                unsafeAtomicAdd(b + 64 * k + 0, ac[k].x);
                unsafeAtomicAdd(b + 64 * k + 1, ac[k].y);
                unsafeAtomicAdd(b + 64 * k + 2, ac[k].z);
                unsafeAtomicAdd(b + 64 * k + 3, ac[k].w);
            }
        } else {
            // ---------- slow path (~3%: transitions & tails), wave-wide rows ----------
            float ax = 0.f, ay = 0.f, az = 0.f, aw = 0.f;
            int cur = -1;
            const size_t lofs = (size_t)lane * 4;
            for (int t = 0; t < m; ++t) {
                const int r   = __builtin_amdgcn_readfirstlane(__shfl(pr, t, 64));
                const int lab = __builtin_amdgcn_readfirstlane(__shfl(pl, t, 64));
                if (lab != cur) {
                    if (cur >= 0) {
                        float* b = bins + cur * FDIM + lane * 4;
                        unsafeAtomicAdd(b + 0, ax); unsafeAtomicAdd(b + 1, ay);
                        unsafeAtomicAdd(b + 2, az); unsafeAtomicAdd(b + 3, aw);
                    }
                    ax = ay = az = aw = 0.f;
                    cur = lab;
                }
                const float4 v = *reinterpret_cast<const float4*>(
                    feats + (size_t)r * FDIM + lofs);
                const float ss = wave_sum64(v.x * v.x + v.y * v.y + v.z * v.z + v.w * v.w);
                const float inv = 1.0f / fmaxf(sqrtf(ss), 1e-12f);
                ax = fmaf(v.x, inv, ax); ay = fmaf(v.y, inv, ay);
                az = fmaf(v.z, inv, az); aw = fmaf(v.w, inv, aw);
            }
            if (cur >= 0) {
                float* b = bins + cur * FDIM + lane * 4;
                unsafeAtomicAdd(b + 0, ax); unsafeAtomicAdd(b + 1, ay);
                unsafeAtomicAdd(b + 2, az); unsafeAtomicAdd(b + 3, aw);
            }
        }
    }

    __syncthreads();
    // sparse span flush: only classes this block touched
    const int cmin = s_cmin, cmax = s_cmax;
    const int base = cmin * FDIM;
    const int tot = (cmax - cmin + 1) * FDIM;
    for (int i = tid; i < tot; i += MPT) {
        const float vv = bins[base + i];
        if (vv != 0.0f) unsafeAtomicAdd(&g_sums[base + i], vv);
    }
}

// ---------------- bool / scalar dtype detection ----------------
__device__ int detect_bool_enc(const void* p) {
    const unsigned int* u = (const unsigned int*)p;
    bool i32ok = true, f32ok = true;
    for (int i = 0; i < 22; ++i) {
        unsigned int w = u[i];
        if (w > 1u) i32ok = false;
        if (w != 0u && w != 0x3F800000u) f32ok = false;
    }
    return i32ok ? 1 : (f32ok ? 2 : 0);
}
__device__ bool read_bool(const void* p, int enc, int i) {
    if (enc == 1) return ((const unsigned int*)p)[i] != 0u;
    if (enc == 2) return ((const float*)p)[i] != 0.0f;
    return ((const unsigned char*)p)[i] != 0;
}
__device__ int read_step(const void* p) {
    unsigned int w = ((const unsigned int*)p)[0];
    int iv = (int)w;
    if (iv >= 0 && iv < 16777216) return iv;
    return (int)__uint_as_float(w);
}

// ---------------- K5: per-class finalize ----------------
extern "C" __global__ void __launch_bounds__(FDIM)
finalize(const float* __restrict__ g_sums, const unsigned int* __restrict__ hist,
         const float* __restrict__ protos, const void* __restrict__ p_init,
         const float* __restrict__ p_var, const float* __restrict__ shadow,
         const void* __restrict__ s_init, const int* __restrict__ p_count,
         const void* __restrict__ p_step, float* __restrict__ out)
{
    const int c = blockIdx.x;
    const int d = threadIdx.x;

    __shared__ int enc_pi, enc_si;
    __shared__ float red[FDIM / 64];
    __shared__ float s_upd;
    if (d == 0) { enc_pi = detect_bool_enc(p_init); enc_si = detect_bool_enc(s_init); }
    __syncthreads();

    const unsigned int cnt = hist[c];
    const bool present = cnt > 0u;
    const float sum = g_sums[c * FDIM + d];        // natural layout
    const float cls = sum / fmaxf((float)cnt, 1.0f);
    const float oldp = protos[c * FDIM + d];

    const float diff = cls - oldp;
    float ds = wave_sum64(diff * diff);
    if ((d & 63) == 0) red[d >> 6] = ds;
    __syncthreads();
    if (d == 0) s_upd = sqrtf(red[0] + red[1] + red[2] + red[3] + 1e-24f);
    __syncthreads();
    const float upd_mag = s_upd;

    const bool  init  = read_bool(p_init, enc_pi, c);
    const bool  sinit = read_bool(s_init, enc_si, c);
    const float var   = p_var[c];
    const int   step  = read_step(p_step);

    const float progress = fminf(1.0f, (float)step * (1.0f / 2000.0f));
    const float mom = init ? (0.99f + 0.009f * expf(-var) * progress) : 0.99f;

    const float ema   = mom * oldp + (1.0f - mom) * cls;
    const float newp  = present ? (init ? ema : cls) : oldp;

    const float sh     = shadow[c * FDIM + d];
    const float sh_ema = 0.9999f * sh + 0.0001f * newp;
    const float newsh  = present ? (sinit ? sh_ema : newp) : sh;

    const int O1 = NCLS * FDIM;
    const int O2 = O1 + NCLS;
    const int O3 = O2 + NCLS * FDIM;
    const int O4 = O3 + NCLS;
    const int O5 = O4 + NCLS;

    out[c * FDIM + d]       = newp;
    out[O2 + c * FDIM + d]  = newsh;
    if (d == 0) {
        const float newvar = (present && init) ? (0.99f * var + 0.01f * upd_mag) : var;
        out[O1 + c] = newvar;
        out[O3 + c] = (init || present)  ? 1.0f : 0.0f;
        out[O4 + c] = (sinit || present) ? 1.0f : 0.0f;
        out[O5 + c] = (float)(p_count[c] + (present ? 1 : 0));
    }
}

extern "C" void kernel_launch(void* const* d_in, const int* in_sizes, int n_in,
                              void* d_out, int out_size, void* d_ws, size_t ws_size,
                              hipStream_t stream) {
    const float* feats  = (const float*)d_in[0];
    const int*   labels = (const int*)d_in[1];
    const float* protos = (const float*)d_in[2];
    const void*  p_init = d_in[3];
    const float* p_var  = (const float*)d_in[4];
    const float* shadow = (const float*)d_in[5];
    const void*  s_init = d_in[6];
    const int*   p_cnt  = (const int*)d_in[7];
    const void*  p_step = d_in[8];
    const int nrows = in_sizes[1];

    float*        g_sums = (float*)d_ws;
    unsigned int* hist   = (unsigned int*)d_ws + WS_HIST;
    unsigned int* cursor = (unsigned int*)d_ws + WS_CURSOR;
    unsigned int* hpart  = (unsigned int*)d_ws + WS_HPART;
    uint2*        packed = (uint2*)((unsigned int*)d_ws + WS_PACKED);

    hist_k<<<HBLK, HT, 0, stream>>>(labels, hpart, g_sums, nrows);
    prefix_k<<<1, 128, 0, stream>>>(hpart, hist, cursor, HBLK);
    const int scat_blocks = (nrows + SCHUNK - 1) / SCHUNK;
    scatter_k<<<scat_blocks, HT, 0, stream>>>(labels, cursor, packed, nrows);
    const int main_blocks = (nrows + RPB - 1) / RPB;
    mainpass<<<main_blocks, MPT, 0, stream>>>(feats, packed, g_sums, nrows);
    finalize<<<NCLS, FDIM, 0, stream>>>(g_sums, hist, protos, p_init, p_var,
                                        shadow, s_init, p_cnt, p_step, (float*)d_out);
}